// Round 15
// baseline (221.240 us; speedup 1.0000x reference)
//
#include <hip/hip_runtime.h>
#include <hip/hip_fp16.h>

#define NUM_NODES 100000
#define HIDDEN 128
#define NPAIRS 1000000

constexpr int BP = 128;   // pairs per block (fallback kernel)
constexpr int KT = 32;    // k-tile depth (fallback kernel)
constexpr int PAD = 136;  // f16 row stride: 272 B -> 2-way bank aliasing (free, m136)

typedef _Float16 f16;
typedef f16 f16x8 __attribute__((ext_vector_type(8)));
typedef float f32x4 __attribute__((ext_vector_type(4)));

// ---------- idx dtype detection (int64 vs int32), wave-parallel ----------
__global__ void detect_idx64(const unsigned int* __restrict__ raw, int* __restrict__ flag) {
  unsigned v = raw[2 * threadIdx.x + 1];
  unsigned long long b = __ballot(v == 0u);
  if (threadIdx.x == 0) *flag = (b == ~0ull) ? 1 : 0;
}

// Decode one float's bit pattern as 2 halves -> 2 floats. Single-variable cast: well-defined.
static __device__ __forceinline__ float2 h2tof2(float bits) {
  __half2 h = __builtin_bit_cast(__half2, bits);
  return make_float2(__low2float(h), __high2float(h));
}

// ---------- kernel 0: one-time W1 transpose to f16: W1t[h][c][k] = W1[h*128+k][c] ----------
__global__ __launch_bounds__(256) void transpose_w1(
    const float* __restrict__ W1,   // [256][128] fp32
    f16*         __restrict__ W1t)  // [2][128][128] f16, K-contiguous
{
  __shared__ float tile[32][33];
  const int kb = blockIdx.x * 32;
  const int cb = blockIdx.y * 32;
  const int h  = blockIdx.z;
  const int tx = threadIdx.x & 31;
  const int ty = threadIdx.x >> 5;   // 0..7
  #pragma unroll
  for (int i = 0; i < 4; ++i) {
    int k = ty + i * 8;
    tile[k][tx] = W1[(size_t)(h * 128 + kb + k) * HIDDEN + cb + tx];
  }
  __syncthreads();
  #pragma unroll
  for (int i = 0; i < 4; ++i) {
    int c = ty + i * 8;
    W1t[(size_t)h * 16384 + (size_t)(cb + c) * 128 + kb + tx] = (f16)tile[tx][c];
  }
}

// ---------- kernel 1 (MFMA, staging-free): Rh[n, hsel*128+j] = sum_k z[n,k]*W1[hsel*128+k, j] ----------
// A fragments loaded directly from global z (fp32 -> f16 in-register);
// B fragments loaded directly from L2-resident pre-transposed W1t.
// LDS used only for the coalesced D writeback (35 KB -> 4 blocks/CU).
__global__ __launch_bounds__(256) void node_precompute_mfma(
    const float* __restrict__ z,
    const f16*   __restrict__ W1t,   // [2][128][128], K-contiguous (pre-transposed)
    __half*      __restrict__ Rh)
{
  __shared__ __align__(16) f16 Ds[128 * PAD];  // D staging only

  const int tid  = threadIdx.x;
  const int m0   = blockIdx.x * 128;
  const int hsel = blockIdx.y;   // 0 -> P, 1 -> Q

  const int wave  = tid >> 6;
  const int lane  = tid & 63;
  const int lrow  = lane & 15;   // A row / B col / D col
  const int kgrp  = lane >> 4;   // k-chunk (input frags) / row-group (D)
  const int rbase = wave * 32;   // this wave owns rows [rbase, rbase+32)

  // ---- A fragments direct from global: af[rt][k] = z[m0+rbase+rt*16+lrow][k*32+kgrp*8 ..+8]
  f16x8 af[2][4];
  #pragma unroll
  for (int rt = 0; rt < 2; ++rt) {
    int zr = m0 + rbase + rt * 16 + lrow;
    if (zr >= NUM_NODES) zr = NUM_NODES - 1;   // clamp (duplicate row; output guarded)
    const float* zrow = z + (size_t)zr * HIDDEN;
    #pragma unroll
    for (int k = 0; k < 4; ++k) {
      const float4* s = (const float4*)(zrow + k * 32 + kgrp * 8);
      float4 a = s[0], b = s[1];
      f16x8 h;
      h[0] = (f16)a.x; h[1] = (f16)a.y; h[2] = (f16)a.z; h[3] = (f16)a.w;
      h[4] = (f16)b.x; h[5] = (f16)b.y; h[6] = (f16)b.z; h[7] = (f16)b.w;
      af[rt][k] = h;
    }
  }

  f32x4 acc[2][8];
  #pragma unroll
  for (int rt = 0; rt < 2; ++rt)
    #pragma unroll
    for (int ct = 0; ct < 8; ++ct)
      acc[rt][ct] = (f32x4){0.f, 0.f, 0.f, 0.f};

  // ---- B fragments direct from W1t (L2-resident 32 KB per hsel)
  const f16* wbase = W1t + (size_t)hsel * 16384;
  #pragma unroll
  for (int ct = 0; ct < 8; ++ct) {
    f16x8 bf[4];
    #pragma unroll
    for (int k = 0; k < 4; ++k)
      bf[k] = *(const f16x8*)(wbase + (size_t)(ct * 16 + lrow) * 128 + k * 32 + kgrp * 8);
    #pragma unroll
    for (int rt = 0; rt < 2; ++rt)
      #pragma unroll
      for (int k = 0; k < 4; ++k)
        acc[rt][ct] = __builtin_amdgcn_mfma_f32_16x16x32_f16(af[rt][k], bf[k], acc[rt][ct], 0, 0, 0);
  }

  // ---- D -> LDS (f16), m89-verified mapping: col = lane&15, row = (lane>>4)*4 + reg
  #pragma unroll
  for (int rt = 0; rt < 2; ++rt)
    #pragma unroll
    for (int ct = 0; ct < 8; ++ct)
      #pragma unroll
      for (int r = 0; r < 4; ++r) {
        int row = rbase + rt * 16 + kgrp * 4 + r;
        int col = ct * 16 + lrow;
        Ds[row * PAD + col] = (f16)acc[rt][ct][r];
      }
  __syncthreads();

  // ---- coalesced copy-out
  {
    const int row  = tid >> 1;
    const int half = tid & 1;
    int gr = m0 + row;
    if (gr < NUM_NODES) {
      const f16* srcr = Ds + row * PAD + half * 64;
      float4* dst = (float4*)((f16*)Rh + (size_t)gr * 256 + hsel * 128 + half * 64);
      #pragma unroll
      for (int i = 0; i < 8; ++i)
        dst[i] = *(const float4*)(srcr + i * 8);
    }
  }
}

// ---------- kernel 2: per-edge fused relu + dot (fp16 table, 8-lane subgroups) ----------
__global__ __launch_bounds__(256) void edge_pass(
    const __half* __restrict__ Rh,
    const void*   __restrict__ pairs,
    const float*  __restrict__ b1,
    const float*  __restrict__ W2,
    const float*  __restrict__ b2,
    const int*    __restrict__ flag,
    float*        __restrict__ out)
{
  const int tid = threadIdx.x;
  const int ln  = tid & 7;                        // lane within 8-lane subgroup
  const int e   = blockIdx.x * 32 + (tid >> 3);   // one edge per subgroup
  const int is64 = *flag;

  long long u, v;
  if (is64) {
    const long long* q = (const long long*)pairs;
    u = q[2 * e]; v = q[2 * e + 1];
  } else {
    const int* q = (const int*)pairs;
    u = q[2 * e]; v = q[2 * e + 1];
  }

  const float4* Pu = (const float4*)(Rh + (size_t)u * 256 + ln * 16);
  const float4* Qv = (const float4*)(Rh + (size_t)v * 256 + 128 + ln * 16);
  float4 pu0 = Pu[0], pu1 = Pu[1];
  float4 qv0 = Qv[0], qv1 = Qv[1];

  const float4* b1p = (const float4*)(b1 + ln * 16);
  const float4* w2p = (const float4*)(W2 + ln * 16);
  float4 c0 = b1p[0], c1 = b1p[1], c2 = b1p[2], c3 = b1p[3];
  float4 w0 = w2p[0], w1 = w2p[1], w2_ = w2p[2], w3 = w2p[3];

  float s = 0.f;
  {
    float2 p, q;
    p = h2tof2(pu0.x); q = h2tof2(qv0.x);
    s = fmaf(fmaxf(p.x + q.x + c0.x, 0.f), w0.x, s);
    s = fmaf(fmaxf(p.y + q.y + c0.y, 0.f), w0.y, s);
    p = h2tof2(pu0.y); q = h2tof2(qv0.y);
    s = fmaf(fmaxf(p.x + q.x + c0.z, 0.f), w0.z, s);
    s = fmaf(fmaxf(p.y + q.y + c0.w, 0.f), w0.w, s);
    p = h2tof2(pu0.z); q = h2tof2(qv0.z);
    s = fmaf(fmaxf(p.x + q.x + c1.x, 0.f), w1.x, s);
    s = fmaf(fmaxf(p.y + q.y + c1.y, 0.f), w1.y, s);
    p = h2tof2(pu0.w); q = h2tof2(qv0.w);
    s = fmaf(fmaxf(p.x + q.x + c1.z, 0.f), w1.z, s);
    s = fmaf(fmaxf(p.y + q.y + c1.w, 0.f), w1.w, s);
    p = h2tof2(pu1.x); q = h2tof2(qv1.x);
    s = fmaf(fmaxf(p.x + q.x + c2.x, 0.f), w2_.x, s);
    s = fmaf(fmaxf(p.y + q.y + c2.y, 0.f), w2_.y, s);
    p = h2tof2(pu1.y); q = h2tof2(qv1.y);
    s = fmaf(fmaxf(p.x + q.x + c2.z, 0.f), w2_.z, s);
    s = fmaf(fmaxf(p.y + q.y + c2.w, 0.f), w2_.w, s);
    p = h2tof2(pu1.z); q = h2tof2(qv1.z);
    s = fmaf(fmaxf(p.x + q.x + c3.x, 0.f), w3.x, s);
    s = fmaf(fmaxf(p.y + q.y + c3.y, 0.f), w3.y, s);
    p = h2tof2(pu1.w); q = h2tof2(qv1.w);
    s = fmaf(fmaxf(p.x + q.x + c3.z, 0.f), w3.z, s);
    s = fmaf(fmaxf(p.y + q.y + c3.w, 0.f), w3.w, s);
  }

  s += __shfl_xor(s, 1);
  s += __shfl_xor(s, 2);
  s += __shfl_xor(s, 4);

  if (ln == 0) out[e] = s + b2[0];
}

// ---------- FALLBACK: round-1 fused kernel (used if ws too small) ----------
__global__ __launch_bounds__(256) void edge_mlp(
    const float* __restrict__ z,
    const void*  __restrict__ pairs,
    const float* __restrict__ W1,
    const float* __restrict__ b1,
    const float* __restrict__ W2,
    const float* __restrict__ b2,
    const int*   __restrict__ flag,
    float*       __restrict__ out)
{
  __shared__ __align__(16) float Asf[KT][BP];
  __shared__ __align__(16) float Bsf[KT][HIDDEN];

  const int tid = threadIdx.x;
  const int p0  = blockIdx.x * BP;
  const int is64 = *flag;

  const int sp   = tid >> 1;
  const int half = tid & 1;
  const int bk   = tid >> 3;
  const int bc   = (tid & 7) * 16;

  int uu = 0, vv = 0;
  {
    int gp = p0 + sp;
    if (gp < NPAIRS) {
      if (is64) {
        const long long* q = (const long long*)pairs;
        uu = (int)q[2 * gp];
        vv = (int)q[2 * gp + 1];
      } else {
        const int* q = (const int*)pairs;
        uu = q[2 * gp];
        vv = q[2 * gp + 1];
      }
    }
  }

  const int wave  = tid >> 6;
  const int lane  = tid & 63;
  const int pg    = lane >> 3;
  const int cg    = lane & 7;
  const int pbase = (wave >> 1) * 64 + pg * 8;
  const int cbase = (wave & 1)  * 64 + cg * 8;

  float acc[8][8];
  #pragma unroll
  for (int i = 0; i < 8; ++i)
    #pragma unroll
    for (int j = 0; j < 8; ++j) acc[i][j] = 0.f;

  for (int kt = 0; kt < 8; ++kt) {
    {
      const int node = (kt < 4) ? uu : vv;
      const int koff = (kt & 3) * 32 + half * 16;
      const float4* src = (const float4*)(z + (size_t)node * HIDDEN + koff);
      #pragma unroll
      for (int i = 0; i < 4; ++i) {
        float4 v4 = src[i];
        int tk = half * 16 + 4 * i;
        Asf[tk + 0][sp] = v4.x;
        Asf[tk + 1][sp] = v4.y;
        Asf[tk + 2][sp] = v4.z;
        Asf[tk + 3][sp] = v4.w;
      }
    }
    {
      const float4* src = (const float4*)(W1 + (size_t)(kt * KT + bk) * HIDDEN + bc);
      float4* dst = (float4*)&Bsf[bk][bc];
      #pragma unroll
      for (int i = 0; i < 4; ++i) dst[i] = src[i];
    }
    __syncthreads();

    #pragma unroll 8
    for (int k = 0; k < KT; ++k) {
      float4 a0  = *(const float4*)&Asf[k][pbase];
      float4 a1  = *(const float4*)&Asf[k][pbase + 4];
      float4 bb0 = *(const float4*)&Bsf[k][cbase];
      float4 bb1 = *(const float4*)&Bsf[k][cbase + 4];
      float av[8] = {a0.x, a0.y, a0.z, a0.w, a1.x, a1.y, a1.z, a1.w};
      float bv[8] = {bb0.x, bb0.y, bb0.z, bb0.w, bb1.x, bb1.y, bb1.z, bb1.w};
      #pragma unroll
      for (int i = 0; i < 8; ++i)
        #pragma unroll
        for (int j = 0; j < 8; ++j)
          acc[i][j] = fmaf(av[i], bv[j], acc[i][j]);
    }
    __syncthreads();
  }

  float b1v[8], w2v[8];
  #pragma unroll
  for (int j = 0; j < 8; ++j) {
    b1v[j] = b1[cbase + j];
    w2v[j] = W2[cbase + j];
  }
  float psum[8];
  #pragma unroll
  for (int i = 0; i < 8; ++i) {
    float s = 0.f;
    #pragma unroll
    for (int j = 0; j < 8; ++j) {
      float h = fmaxf(acc[i][j] + b1v[j], 0.f);
      s = fmaf(h, w2v[j], s);
    }
    psum[i] = s;
  }

  float* red = &Asf[0][0];
  const int cidx = (wave & 1) * 8 + cg;
  #pragma unroll
  for (int i = 0; i < 8; ++i) red[(pbase + i) * 16 + cidx] = psum[i];
  __syncthreads();

  if (tid < BP) {
    float s = b2[0];
    #pragma unroll
    for (int j = 0; j < 16; ++j) s += red[tid * 16 + j];
    int gp = p0 + tid;
    if (gp < NPAIRS) out[gp] = s;
  }
}

extern "C" void kernel_launch(void* const* d_in, const int* in_sizes, int n_in,
                              void* d_out, int out_size, void* d_ws, size_t ws_size,
                              hipStream_t stream) {
  const float* z     = (const float*)d_in[0];
  const void*  pairs =               d_in[1];
  const float* W1    = (const float*)d_in[2];
  const float* b1    = (const float*)d_in[3];
  const float* W2    = (const float*)d_in[4];
  const float* b2    = (const float*)d_in[5];
  float* out = (float*)d_out;

  const size_t R_BYTES   = (size_t)NUM_NODES * 256 * sizeof(__half);  // 51.2 MB
  const size_t W1T_BYTES = (size_t)2 * 128 * 128 * sizeof(f16);       // 64 KB

  if (ws_size >= R_BYTES + W1T_BYTES + 256) {
    __half* Rh  = (__half*)d_ws;
    f16*    W1t = (f16*)((char*)d_ws + R_BYTES);
    int*    flag = (int*)((char*)d_ws + R_BYTES + W1T_BYTES);
    transpose_w1<<<dim3(4, 4, 2), 256, 0, stream>>>(W1, W1t);
    detect_idx64<<<1, 64, 0, stream>>>((const unsigned int*)pairs, flag);
    dim3 grid1((NUM_NODES + 127) / 128, 2);
    node_precompute_mfma<<<grid1, 256, 0, stream>>>(z, W1t, Rh);
    edge_pass<<<NPAIRS / 32, 256, 0, stream>>>(Rh, pairs, b1, W2, b2, flag, out);
  } else {
    int* flag = (int*)d_ws;
    detect_idx64<<<1, 64, 0, stream>>>((const unsigned int*)pairs, flag);
    const int grid = (NPAIRS + BP - 1) / BP;
    edge_mlp<<<grid, 256, 0, stream>>>(z, pairs, W1, b1, W2, b2, flag, out);
  }
}